// Round 14
// baseline (185.548 us; speedup 1.0000x reference)
//
#include <hip/hip_runtime.h>
#include <hip/hip_fp16.h>
#include <stdint.h>

#define M_TOK 8192
#define KD 4096
#define ND 4096

using i32x4 = __attribute__((ext_vector_type(4))) int;
using f32x4 = __attribute__((ext_vector_type(4))) float;

typedef const __attribute__((address_space(1))) void* gp_t;
typedef __attribute__((address_space(3))) void* lp_t;

// ---------------- Kernel 1: fused per-token quant (blocks 0..8191) + weight pack (blocks 8192..) ----------------
__global__ __launch_bounds__(256) void prep_kernel(
    const float* __restrict__ x,
    int8_t* __restrict__ q,
    float* __restrict__ scales,
    const int* __restrict__ w32,
    int8_t* __restrict__ w8)
{
    const int t = threadIdx.x;
    if (blockIdx.x >= 8192) {
        const int b = blockIdx.x - 8192;          // 0..4095
        const int4* w4 = (const int4*)w32;
        int* q32 = (int*)w8;
        #pragma unroll
        for (int u = 0; u < 4; ++u) {
            int g = b * 1024 + u * 256 + t;
            int4 a = w4[g];
            q32[g] = (a.x & 255) | ((a.y & 255) << 8) | ((a.z & 255) << 16) | (a.w << 24);
        }
        return;
    }

    const int row  = blockIdx.x;
    const int lane = t & 63;
    const int wave = t >> 6;

    const float4* xr = (const float4*)(x + (size_t)row * KD);
    float4 p[4];
    #pragma unroll
    for (int i = 0; i < 4; ++i) p[i] = xr[i * 256 + t];

    float am = 0.0f;
    #pragma unroll
    for (int i = 0; i < 4; ++i) {
        am = fmaxf(am, fmaxf(fmaxf(fabsf(p[i].x), fabsf(p[i].y)),
                             fmaxf(fabsf(p[i].z), fabsf(p[i].w))));
    }
    #pragma unroll
    for (int off = 32; off >= 1; off >>= 1)
        am = fmaxf(am, __shfl_xor(am, off));

    __shared__ float smax[4];
    if (lane == 0) smax[wave] = am;
    __syncthreads();
    am = fmaxf(fmaxf(smax[0], smax[1]), fmaxf(smax[2], smax[3]));

    float s = __half2float(__float2half(am * (1.0f / 127.0f)));
    s = fmaxf(s, 1e-30f);
    const float inv = 1.0f / s;

    int* qr = (int*)(q + (size_t)row * KD);
    #pragma unroll
    for (int i = 0; i < 4; ++i) {
        float vv[4] = {p[i].x, p[i].y, p[i].z, p[i].w};
        int w32v = 0;
        #pragma unroll
        for (int e = 0; e < 4; ++e) {
            float tq = __half2float(__float2half(vv[e] * inv));
            int qi = (int)rintf(tq);
            qi = max(-127, min(127, qi));
            w32v |= (qi & 255) << (8 * e);
        }
        qr[i * 256 + t] = w32v;
    }
    if (t == 0) scales[row] = s;
}

// ---------------- 256x128-tile 4-wave int8 GEMM, BK=64, high register-blocking (acc 8x4) ----------------
// LDS per buffer: A 16 KB + B 8 KB, paired-row layout: logical row r, k (0..63):
//   i = r>>1, c0 = k + 64*(r&1), phys = i*128 + (c0 ^ ((i&7)<<4))   [st-16x32 XOR on 128-B phys rows]
// Fragment read (16-lane beats) spreads all 8 slots -> 2-way max (free).
// DMA: linear dest + exact inverse-swizzled global source (rule #21).
// Per wave (2x2 of 4): output 128x64 = 8mf x 4nf of 16x16; acc = 128 regs; 12 ds_reads : 32 MFMA per phase.

__device__ __forceinline__ void mfma_32(i32x4 (&acc)[8][4],
                                        const i32x4 (&a)[8],
                                        const i32x4 (&b)[4]) {
    __builtin_amdgcn_s_setprio(1);
    #pragma unroll
    for (int mf = 0; mf < 8; ++mf)
        #pragma unroll
        for (int nf = 0; nf < 4; ++nf)
            acc[mf][nf] = __builtin_amdgcn_mfma_i32_16x16x64_i8(a[mf], b[nf], acc[mf][nf], 0, 0, 0);
    __builtin_amdgcn_s_setprio(0);
}

#define BAR()   __builtin_amdgcn_s_barrier()
#define LGKM0() asm volatile("s_waitcnt lgkmcnt(0)" ::: "memory")
#define VM6()   asm volatile("s_waitcnt vmcnt(6)")

__global__ __launch_bounds__(256, 2) void gemm_q8_hrb_kernel(
    const int8_t* __restrict__ q,
    const int8_t* __restrict__ w8,
    const float* __restrict__ qs,
    const float* __restrict__ wscale,
    const float* __restrict__ bias,
    float* __restrict__ y)
{
    __shared__ char lds[2][24576];   // [buf][A 16KB | B 8KB] = 48 KiB -> 2 blocks/CU

    const int tid  = threadIdx.x;
    const int lane = tid & 63;
    const int wave = tid >> 6;     // 0..3
    const int wr   = wave >> 1;    // 0..1  (M half: 128 rows)
    const int wc   = wave & 1;     // 0..1  (N half: 64 cols)

    // XCD-chunked bijective swizzle: 1024 blocks, 128/XCD; within XCD consecutive share tm (A-panel)
    const int bid = blockIdx.x;               // 0..1023
    const int sid = (bid & 7) * 128 + (bid >> 3);
    const int tn  = sid & 31;                 // 0..31
    const int tm  = sid >> 5;                 // 0..31

    const int8_t* gA = q  + (size_t)(tm * 256) * KD;
    const int8_t* gB = w8 + (size_t)(tn * 128) * KD;

    // fragment byte offsets (within operand region)
    const int l15 = lane & 15;
    const int cg  = (lane >> 4) << 4;                // k-group 0/16/32/48
    const int swz = ((l15 >> 1) & 7) << 4;
    const int c0  = (cg + 64 * (l15 & 1)) ^ swz;     // swizzled phys col
    unsigned aoff[8], boff[4];
    #pragma unroll
    for (int mf = 0; mf < 8; ++mf)
        aoff[mf] = (unsigned)((wr * 64 + mf * 8 + (l15 >> 1)) * 128 + c0);
    #pragma unroll
    for (int nf = 0; nf < 4; ++nf)
        boff[nf] = (unsigned)((wc * 32 + nf * 8 + (l15 >> 1)) * 128 + c0);

    // DMA source mapping (inverse of paired-row swizzle); dest linear = ch*4096 + tid*16
    int goff[4];
    #pragma unroll
    for (int ch = 0; ch < 4; ++ch) {
        const int d  = ch * 4096 + tid * 16;
        const int i  = d >> 7;
        const int sp = (d >> 4) & 7;
        const int s  = sp ^ (i & 7);
        const int r  = 2 * i + (s >> 2);
        const int k  = (s & 3) * 16;
        goff[ch] = r * KD + k;
    }
    const int ldso = tid * 16;

    #define STAGE(kbyte, buf)                                                                         \
        do {                                                                                          \
            char* _lA = &lds[buf][0];                                                                 \
            char* _lB = &lds[buf][16384];                                                             \
            __builtin_amdgcn_global_load_lds((gp_t)(gA + (kbyte) + goff[0]), (lp_t)(_lA + ldso),          16, 0, 0); \
            __builtin_amdgcn_global_load_lds((gp_t)(gA + (kbyte) + goff[1]), (lp_t)(_lA + 4096 + ldso),   16, 0, 0); \
            __builtin_amdgcn_global_load_lds((gp_t)(gA + (kbyte) + goff[2]), (lp_t)(_lA + 8192 + ldso),   16, 0, 0); \
            __builtin_amdgcn_global_load_lds((gp_t)(gA + (kbyte) + goff[3]), (lp_t)(_lA + 12288 + ldso),  16, 0, 0); \
            __builtin_amdgcn_global_load_lds((gp_t)(gB + (kbyte) + goff[0]), (lp_t)(_lB + ldso),          16, 0, 0); \
            __builtin_amdgcn_global_load_lds((gp_t)(gB + (kbyte) + goff[1]), (lp_t)(_lB + 4096 + ldso),   16, 0, 0); \
        } while (0)

    #define READS(buf)                                                                   \
        do {                                                                             \
            const char* _lA = &lds[buf][0];                                              \
            const char* _lB = &lds[buf][16384];                                          \
            _Pragma("unroll")                                                            \
            for (int mf = 0; mf < 8; ++mf) a[mf] = *(const i32x4*)(_lA + aoff[mf]);      \
            _Pragma("unroll")                                                            \
            for (int nf = 0; nf < 4; ++nf) b[nf] = *(const i32x4*)(_lB + boff[nf]);      \
        } while (0)

    i32x4 acc[8][4] = {};
    i32x4 a[8], b[4];

    // prologue: kt0 -> buf0, kt1 -> buf1 (12 loads)
    STAGE(0,  0);
    STAGE(64, 1);
    VM6();   // kt0 landed
    BAR();

    for (int it = 0; it < 31; ++it) {
        const int kb2 = (2 * it + 2) * 64;
        const int kb3 = (2 * it + 3) * 64;

        // even phase: buf0
        READS(0);
        LGKM0();            // own reads done
        BAR();              // all waves' reads done -> buf0 free
        STAGE(kb2, 0);
        mfma_32(acc, a, b);
        VM6();              // kt+1 landed
        BAR();

        // odd phase: buf1
        READS(1);
        LGKM0();
        BAR();
        STAGE(kb3, 1);
        mfma_32(acc, a, b);
        VM6();              // kt+2 landed -> buf0 ready
        BAR();
    }

    // tail: kt=62 (buf0), kt=63 (buf1) — no staging
    READS(0);
    LGKM0();
    BAR();
    mfma_32(acc, a, b);
    asm volatile("s_waitcnt vmcnt(0)");   // kt63 + everything landed
    BAR();

    READS(1);
    LGKM0();
    BAR();
    mfma_32(acc, a, b);
    BAR();   // all reads drained (LGKM0 above), all DMA drained -> LDS reusable

    // ---------------- epilogue: 4 passes of 64 block-rows; LDS transpose + full-line nt stores ----------------
    // pass p: rows 64p..64p+63 (owned by wr=p>>1, mf in {4(p&1)..}); LDS 64 rows x 128 cols f32 (32 KB)
    // write phys = rl*512 + ((cl*4) ^ ((rl&31)<<4)); read 16B blocks with same XOR: both <=2-way.
    {
        char* eld = &lds[0][0];
        const int g = lane >> 4;
        #pragma unroll
        for (int p = 0; p < 4; ++p) {
            if (wr == (p >> 1)) {
                #pragma unroll
                for (int mq = 0; mq < 4; ++mq) {
                    const int mf  = (p & 1) * 4 + mq;
                    const int rmb = tm * 256 + wr * 128 + mf * 16 + g * 4;
                    float qsv[4];
                    #pragma unroll
                    for (int r = 0; r < 4; ++r) qsv[r] = qs[rmb + r];
                    #pragma unroll
                    for (int nf = 0; nf < 4; ++nf) {
                        const int n  = tn * 128 + wc * 64 + nf * 16 + l15;
                        const float wn = wscale[n];
                        const float bn = bias[n];
                        const int cl = wc * 64 + nf * 16 + l15;
                        #pragma unroll
                        for (int r = 0; r < 4; ++r) {
                            const int rl = mq * 16 + g * 4 + r;
                            const float val = (float)acc[mf][nf][r] * (qsv[r] * wn) + bn;
                            *(float*)(eld + rl * 512 + ((cl * 4) ^ ((rl & 31) << 4))) = val;
                        }
                    }
                }
            }
            __builtin_amdgcn_s_barrier();
            // store: 32 threads per row, 8 rows per iter, 8 iters
            const int c32 = tid & 31;
            const int r8  = tid >> 5;
            const int gcol = tn * 128 + c32 * 4;
            #pragma unroll
            for (int k = 0; k < 8; ++k) {
                const int rl = r8 + k * 8;
                const f32x4 v = *(const f32x4*)(eld + rl * 512 + ((c32 * 16) ^ ((rl & 31) << 4)));
                const int grow = tm * 256 + p * 64 + rl;
                __builtin_nontemporal_store(v, (f32x4*)(y + (size_t)grow * ND + gcol));
            }
            __builtin_amdgcn_s_barrier();
        }
    }
    #undef STAGE
    #undef READS
}

// ---------------- Fallback GEMM (no-workspace path): 128^2 m97 structure, reads w32 ----------------
__global__ __launch_bounds__(256, 2) void gemm_q8_fallback(
    const int8_t* __restrict__ q,
    const int* __restrict__ w32,
    const float* __restrict__ qs,
    const float* __restrict__ wscale,
    const float* __restrict__ bias,
    float* __restrict__ y)
{
    __shared__ int8_t lA[128 * 64];
    __shared__ int8_t lB[128 * 64];

    const int tid  = threadIdx.x;
    const int lane = tid & 63;
    const int wave = tid >> 6;
    const int wr   = wave >> 1;
    const int wc   = wave & 1;
    const int tn   = blockIdx.x;
    const int tm   = blockIdx.y;

    const int ci0  = wave * 2;
    const int off0 = ci0 * 1024 + lane * 16;
    const int r0   = off0 >> 6;
    const int c0   = off0 & 63;
    const int off1 = off0 + 1024;
    const int r1   = off1 >> 6;
    const int c1   = off1 & 63;

    const int8_t* gA0 = q + (size_t)(tm * 128 + r0) * KD + c0;
    const int8_t* gA1 = q + (size_t)(tm * 128 + r1) * KD + c1;

    const int brow  = tid >> 1;
    const int bhalf = tid & 1;
    const int* gW = w32 + (size_t)(tn * 128 + brow) * KD + bhalf * 32;

    i32x4 acc[4][4] = {};
    const int kc = (lane >> 4) * 16;
    const int rA = wr * 64 + (lane & 15);
    const int rB = wc * 64 + (lane & 15);

    for (int k0 = 0; k0 < KD; k0 += 64) {
        __builtin_amdgcn_global_load_lds((gp_t)(gA0 + k0), (lp_t)(lA + ci0 * 1024),        16, 0, 0);
        __builtin_amdgcn_global_load_lds((gp_t)(gA1 + k0), (lp_t)(lA + ci0 * 1024 + 1024), 16, 0, 0);
        int bw[8];
        #pragma unroll
        for (int u = 0; u < 8; ++u) {
            i32x4 a4 = *(const i32x4*)(gW + k0 + u * 4);
            bw[u] = (a4[0] & 255) | ((a4[1] & 255) << 8) | ((a4[2] & 255) << 16) | (a4[3] << 24);
        }
        *(i32x4*)(lB + brow * 64 + bhalf * 32)      = i32x4{bw[0], bw[1], bw[2], bw[3]};
        *(i32x4*)(lB + brow * 64 + bhalf * 32 + 16) = i32x4{bw[4], bw[5], bw[6], bw[7]};
        __syncthreads();

        i32x4 a[4], b[4];
        #pragma unroll
        for (int i = 0; i < 4; ++i) a[i] = *(const i32x4*)(lA + (rA + i * 16) * 64 + kc);
        #pragma unroll
        for (int j = 0; j < 4; ++j) b[j] = *(const i32x4*)(lB + (rB + j * 16) * 64 + kc);
        #pragma unroll
        for (int i = 0; i < 4; ++i)
            #pragma unroll
            for (int j = 0; j < 4; ++j)
                acc[i][j] = __builtin_amdgcn_mfma_i32_16x16x64_i8(a[i], b[j], acc[i][j], 0, 0, 0);
        __syncthreads();
    }

    const int cbase = tn * 128 + wc * 64 + (lane & 15);
    const int rbase = tm * 128 + wr * 64 + ((lane >> 4) << 2);
    #pragma unroll
    for (int j = 0; j < 4; ++j) {
        const int n  = cbase + j * 16;
        const float wn = wscale[n];
        const float bn = bias[n];
        #pragma unroll
        for (int i = 0; i < 4; ++i)
            #pragma unroll
            for (int r = 0; r < 4; ++r) {
                const int m = rbase + i * 16 + r;
                y[(size_t)m * ND + n] = (float)acc[i][j][r] * (qs[m] * wn) + bn;
            }
    }
}

extern "C" void kernel_launch(void* const* d_in, const int* in_sizes, int n_in,
                              void* d_out, int out_size, void* d_ws, size_t ws_size,
                              hipStream_t stream) {
    const float* x      = (const float*)d_in[0];
    const int*   w32    = (const int*)d_in[1];
    const float* wscale = (const float*)d_in[2];
    const float* bias   = (const float*)d_in[3];
    float*       y      = (float*)d_out;

    const size_t q_bytes  = (size_t)M_TOK * KD;
    const size_t s_bytes  = (size_t)M_TOK * sizeof(float);
    const size_t w8_bytes = (size_t)ND * KD;

    int8_t* qbuf   = (int8_t*)d_ws;
    float*  scales = (float*)((char*)d_ws + q_bytes);
    int8_t* w8     = (int8_t*)((char*)d_ws + q_bytes + s_bytes);

    if (ws_size >= q_bytes + s_bytes + w8_bytes) {
        prep_kernel<<<8192 + 4096, 256, 0, stream>>>(x, qbuf, scales, w32, w8);
        gemm_q8_hrb_kernel<<<1024, 256, 0, stream>>>(qbuf, w8, scales, wscale, bias, y);
    } else {
        prep_kernel<<<8192, 256, 0, stream>>>(x, qbuf, scales, w32, w8);
        dim3 grid(ND / 128, M_TOK / 128);
        gemm_q8_fallback<<<grid, 256, 0, stream>>>(qbuf, w32, scales, wscale, bias, y);
    }
}